// Round 14
// baseline (499.614 us; speedup 1.0000x reference)
//
#include <hip/hip_runtime.h>
#include <hip/hip_bf16.h>
#include <stdint.h>

// GAT layer, MI355X. N=8192, F_in=256, F_out=128. All-f32 I/O.
// R14: k_attn main loop has NO LDS and NO barriers — B-frags loaded directly from
// global hT (same address formula as the validated HS reads), adj prefetch depth 2,
// h prefetch rotated in two 4-col-tile groups. Barrier drain (s_waitcnt vmcnt(0)
// before s_barrier) eliminated => prefetches genuinely stay in flight.
// k_xw (fused wa/s1/s2) / k_max / k_comb unchanged from green R13.

#define N_NODES 8192
#define F_INF   256
#define F_OUT   128
#define LRELU   0.01f

typedef __bf16 bf16x8 __attribute__((ext_vector_type(8)));
typedef float  f32x4  __attribute__((ext_vector_type(4)));
using bf16 = __hip_bfloat16;

__device__ __forceinline__ float b2f(bf16 v) { return __bfloat162float(v); }
__device__ __forceinline__ bf16  f2b(float v) { return __float2bfloat16(v); }

// ---------------- kernel 1: hT = bf16(x@W); fused wa = W@a, s1/s2 = x@wa (fp32) ----------------
__global__ __launch_bounds__(256) void k_xw(const float* __restrict__ x,
                                            const float* __restrict__ W,
                                            const float* __restrict__ a,
                                            bf16* __restrict__ hT,
                                            float* __restrict__ s1,
                                            float* __restrict__ s2) {
    __shared__ __align__(16) bf16 WT[F_OUT][F_INF + 8];  // 67.6 KB
    __shared__ __align__(16) bf16 XS[64][72];            // 9.2 KB
    __shared__ float waL[2 * F_INF];
    __shared__ float s1L[64], s2L[64];
    const int tid  = threadIdx.x;
    const int lane = tid & 63, wave = tid >> 6;
    const int i0   = blockIdx.x * 64;
    waL[tid] = 0.f; waL[F_INF + tid] = 0.f;
    if (tid < 64) { s1L[tid] = 0.f; s2L[tid] = 0.f; }
    __syncthreads();
    for (int idx = tid; idx < (F_INF * F_OUT) / 8; idx += 256) {
        int k  = idx >> 4;
        int n0 = (idx & 15) * 8;
        const float* src = W + (size_t)k * F_OUT + n0;
        float4 va = *(const float4*)(src);
        float4 vb = *(const float4*)(src + 4);
        float v[8] = {va.x, va.y, va.z, va.w, vb.x, vb.y, vb.z, vb.w};
        float p1 = 0.f, p2 = 0.f;
#pragma unroll
        for (int c = 0; c < 8; ++c) {
            WT[n0 + c][k] = f2b(v[c]);
            p1 += v[c] * a[n0 + c];
            p2 += v[c] * a[F_OUT + n0 + c];
        }
        atomicAdd(&waL[k], p1);
        atomicAdd(&waL[F_INF + k], p2);
    }
    __syncthreads();
    f32x4 acc[8];
#pragma unroll
    for (int t = 0; t < 8; ++t) acc[t] = {0.f, 0.f, 0.f, 0.f};
    const int m = lane & 15, quad = lane >> 4;
    const int rt = wave;
    for (int kc = 0; kc < F_INF / 64; ++kc) {
        const int k0 = kc * 64;
        {
            int part = tid & 7;
            int r    = tid >> 3;
#pragma unroll
            for (int p = 0; p < 2; ++p) {
                int rr = r + p * 32;
                const float* src = x + (size_t)(i0 + rr) * F_INF + k0 + part * 8;
                float4 va = *(const float4*)(src);
                float4 vb = *(const float4*)(src + 4);
                float v[8] = {va.x, va.y, va.z, va.w, vb.x, vb.y, vb.z, vb.w};
                __align__(16) bf16 th[8];
                float q1 = 0.f, q2 = 0.f;
#pragma unroll
                for (int c = 0; c < 8; ++c) {
                    th[c] = f2b(v[c]);
                    q1 += v[c] * waL[k0 + part * 8 + c];
                    q2 += v[c] * waL[F_INF + k0 + part * 8 + c];
                }
                *(uint4*)(&XS[rr][part * 8]) = *(const uint4*)th;
                atomicAdd(&s1L[rr], q1);
                atomicAdd(&s2L[rr], q2);
            }
        }
        __syncthreads();
#pragma unroll
        for (int ks = 0; ks < 2; ++ks) {
            bf16x8 af = *(const bf16x8*)(&XS[rt * 16 + m][ks * 32 + quad * 8]);
#pragma unroll
            for (int ct = 0; ct < 8; ++ct) {
                bf16x8 bfr = *(const bf16x8*)(&WT[ct * 16 + m][kc * 64 + ks * 32 + quad * 8]);
                acc[ct] = __builtin_amdgcn_mfma_f32_16x16x32_bf16(af, bfr, acc[ct], 0, 0, 0);
            }
        }
        __syncthreads();
    }
#pragma unroll
    for (int ct = 0; ct < 8; ++ct) {
        const int f = ct * 16 + m;
#pragma unroll
        for (int r = 0; r < 4; ++r) {
            const int i = i0 + rt * 16 + quad * 4 + r;
            hT[(size_t)f * N_NODES + i] = f2b(acc[ct][r]);
        }
    }
    if (tid < 64) { s1[i0 + tid] = s1L[tid]; s2[i0 + tid] = s2L[tid]; }
}

// ---------------- kernel 2: global max of s2 ----------------
__global__ __launch_bounds__(256) void k_max(const float* __restrict__ s2,
                                             float* __restrict__ mg) {
    __shared__ float red[256];
    int tid = threadIdx.x;
    float m = -1e30f;
    for (int j = tid; j < N_NODES; j += 256) m = fmaxf(m, s2[j]);
    red[tid] = m;
    __syncthreads();
    for (int s = 128; s > 0; s >>= 1) {
        if (tid < s) red[tid] = fmaxf(red[tid], red[tid + s]);
        __syncthreads();
    }
    if (tid == 0) mg[0] = red[0];
}

// ---------------- kernel 3: flash attention, barrier-free K-loop ----------------
// 64 rows x 1024-col j-octant per block; 4 waves; wave = 16-row tile, all 8 col-tiles.
// Lane (m,quad): A-frag = P[wave*16+m][kh*32+quad*8..+7] computed in regs;
// B-frag = 16B global load hT[(c*16+m)*N + jbase + jc*64 + kh*32 + quad*8].
__global__ __launch_bounds__(256) void k_attn(const int* __restrict__ adj,
                                              const float* __restrict__ s1g,
                                              const float* __restrict__ s2g,
                                              const float* __restrict__ mg,
                                              const bf16* __restrict__ hT,
                                              float* __restrict__ Of,
                                              float* __restrict__ lp) {
    __shared__ float s2s[1024];   // 4 KB, staged once
    const int tid  = threadIdx.x;
    const int lane = tid & 63, wave = tid >> 6;
    const int m = lane & 15, quad = lane >> 4;
    const int i0    = blockIdx.x * 64;
    const int jq    = blockIdx.y;
    const int jbase = jq * 1024;
    const int irow  = i0 + wave * 16 + m;
    const float s1v = s1g[irow];
    const float tmi = s1v + mg[0];
    const float mi  = fmaxf(tmi, LRELU * tmi);  // >= every masked e of this row
    *(float4*)&s2s[tid * 4] = *(const float4*)(s2g + jbase + tid * 4);
    // lane-constant part of the B-frag address
    const bf16* hlane = hT + (size_t)m * N_NODES + jbase + quad * 8;
    // adj prefetch depth 2
    const int4* arowp = (const int4*)(adj + (size_t)irow * N_NODES + jbase);
    int4 avA[4], avB[4];
    avA[0] = arowp[quad * 2];          avA[1] = arowp[quad * 2 + 1];
    avA[2] = arowp[8 + quad * 2];      avA[3] = arowp[8 + quad * 2 + 1];
    avB[0] = arowp[16 + quad * 2];     avB[1] = arowp[16 + quad * 2 + 1];
    avB[2] = arowp[16 + 8 + quad * 2]; avB[3] = arowp[16 + 8 + quad * 2 + 1];
    // h-frag prefetch: group A = col-tiles 0..3, group B = col-tiles 4..7
    uint4 hA[8], hB[8];
#pragma unroll
    for (int c = 0; c < 4; ++c)
#pragma unroll
        for (int kh = 0; kh < 2; ++kh)
            hA[c * 2 + kh] = *(const uint4*)(hlane + (size_t)(c * 16) * N_NODES + kh * 32);
    float lacc = 0.f;
    f32x4 acc[8];
#pragma unroll
    for (int c = 0; c < 8; ++c) acc[c] = {0.f, 0.f, 0.f, 0.f};
    __syncthreads();   // s2s ready — the ONLY barrier

    for (int jc = 0; jc < 16; ++jc) {
        const int jo = jc * 64;
        // issue group-B loads for this chunk (consumed after P-compute + group-A MFMAs)
#pragma unroll
        for (int c = 0; c < 4; ++c)
#pragma unroll
            for (int kh = 0; kh < 2; ++kh)
                hB[c * 2 + kh] = *(const uint4*)(hlane + (size_t)((c + 4) * 16) * N_NODES + jo + kh * 32);
        // P-compute(jc) from prefetched adj (avA) + s2s
        bf16x8 afrag[2];
#pragma unroll
        for (int kh = 0; kh < 2; ++kh) {
            const int am[8] = {avA[kh*2].x, avA[kh*2].y, avA[kh*2].z, avA[kh*2].w,
                               avA[kh*2+1].x, avA[kh*2+1].y, avA[kh*2+1].z, avA[kh*2+1].w};
            const float* s2p = &s2s[jo + kh * 32 + quad * 8];
            __align__(16) bf16 a8[8];
#pragma unroll
            for (int t = 0; t < 8; ++t) {
                float e = s1v + s2p[t];
                e = fmaxf(e, LRELU * e);
                float w = (am[t] > 0) ? __expf(e - mi) : 0.f;
                bf16 bb = f2b(w);
                a8[t] = bb;
                lacc += b2f(bb);
            }
            afrag[kh] = *(const bf16x8*)a8;
        }
        // rotate adj prefetch: avA <- avB, avB <- chunk jc+2
#pragma unroll
        for (int q = 0; q < 4; ++q) avA[q] = avB[q];
        if (jc < 14) {
            const int base = (jc + 2) * 16;
            avB[0] = arowp[base + quad * 2];     avB[1] = arowp[base + quad * 2 + 1];
            avB[2] = arowp[base + 8 + quad * 2]; avB[3] = arowp[base + 8 + quad * 2 + 1];
        }
        // MFMA group A (col-tiles 0..3) from hA
#pragma unroll
        for (int kh = 0; kh < 2; ++kh)
#pragma unroll
            for (int c = 0; c < 4; ++c)
                acc[c] = __builtin_amdgcn_mfma_f32_16x16x32_bf16(
                    afrag[kh], *(const bf16x8*)&hA[c * 2 + kh], acc[c], 0, 0, 0);
        // issue group-A loads for next chunk
        if (jc < 15) {
#pragma unroll
            for (int c = 0; c < 4; ++c)
#pragma unroll
                for (int kh = 0; kh < 2; ++kh)
                    hA[c * 2 + kh] = *(const uint4*)(hlane + (size_t)(c * 16) * N_NODES + jo + 64 + kh * 32);
        }
        // MFMA group B (col-tiles 4..7) from hB
#pragma unroll
        for (int kh = 0; kh < 2; ++kh)
#pragma unroll
            for (int c = 0; c < 4; ++c)
                acc[c + 4] = __builtin_amdgcn_mfma_f32_16x16x32_bf16(
                    afrag[kh], *(const bf16x8*)&hB[c * 2 + kh], acc[c + 4], 0, 0, 0);
    }
    // l: reduce over quads; each row owned by exactly one (wave,m)
    lacc += __shfl_xor(lacc, 16);
    lacc += __shfl_xor(lacc, 32);
    if (quad == 0) lp[(size_t)jq * N_NODES + irow] = lacc;
    // Of: C/D col=m -> f, row=quad*4+r -> i
#pragma unroll
    for (int c = 0; c < 8; ++c) {
        const int f = c * 16 + m;
#pragma unroll
        for (int r = 0; r < 4; ++r) {
            const int i = i0 + wave * 16 + quad * 4 + r;
            Of[((size_t)jq * N_NODES + i) * F_OUT + f] = acc[c][r];
        }
    }
}

// ---------------- kernel 4: combine 8 partials, normalize, ELU, f32 out ----------------
__global__ __launch_bounds__(256) void k_comb(const float* __restrict__ Of,
                                              const float* __restrict__ lp,
                                              float* __restrict__ out) {
    size_t gid = (size_t)blockIdx.x * 256 + threadIdx.x;  // i*128+f
    int i = (int)(gid >> 7);
    float s = 0.f, l = 0.f;
#pragma unroll
    for (int q = 0; q < 8; ++q) {
        s += Of[(size_t)q * (N_NODES * (size_t)F_OUT) + gid];
        l += lp[q * N_NODES + i];
    }
    float o = s / l;
    out[gid] = o > 0.f ? o : __expf(o) - 1.f;
}

extern "C" void kernel_launch(void* const* d_in, const int* in_sizes, int n_in,
                              void* d_out, int out_size, void* d_ws, size_t ws_size,
                              hipStream_t stream) {
    (void)out_size; (void)ws_size;
    const float* x   = nullptr;
    const int*   adj = nullptr;
    const float* W   = nullptr;
    const float* a   = nullptr;
    for (int ii = 0; ii < n_in; ++ii) {
        int sz = in_sizes[ii];
        if      (sz == N_NODES * F_INF)  x   = (const float*)d_in[ii];
        else if (sz == F_INF * F_OUT)    W   = (const float*)d_in[ii];
        else if (sz == 2 * F_OUT)        a   = (const float*)d_in[ii];
        else                             adj = (const int*)d_in[ii];
    }
    float* out = (float*)d_out;

    char* ws = (char*)d_ws;
    bf16*  hT = (bf16*)ws;  ws += (size_t)F_OUT * N_NODES * 2;   // 2 MB
    float* s1 = (float*)ws; ws += N_NODES * 4;
    float* s2 = (float*)ws; ws += N_NODES * 4;
    float* mg = (float*)ws; ws += 256;
    float* lp = (float*)ws; ws += 8 * N_NODES * 4;               // 256 KB
    float* Of = (float*)ws;                                      // 32 MB

    k_xw  <<<N_NODES / 64, 256, 0, stream>>>(x, W, a, hT, s1, s2);
    k_max <<<1, 256, 0, stream>>>(s2, mg);
    k_attn<<<dim3(N_NODES / 64, 8), 256, 0, stream>>>(adj, s1, s2, mg, hT, Of, lp);
    k_comb<<<(N_NODES * F_OUT) / 256, 256, 0, stream>>>(Of, lp, out);
}